// Round 1
// baseline (2178.765 us; speedup 1.0000x reference)
//
#include <hip/hip_runtime.h>
#include <hip/hip_bf16.h>

#define Bb 8
#define Tt 600
#define Cc 8
#define Ff 257
#define TAPS 5
#define DELAY 3
#define KC 40            // TAPS*C
#define NC 48            // KC + C (R columns | P columns)
#define RPW 53           // RP row stride (float2): 106 dwords, gcd(106%32=10,32)=2 -> 16-bank spread
#define TQ 593           // T - DELAY - TAPS + 1
#define TP 602           // Y LDS row stride (float2): conflict-free for channel-strided access
#define EPSF 1e-10f
#define NTOT (Bb*Tt*Cc*Ff)   // 9,868,800

// acc += conj(a)*b with a pre-scaled: (ax,ay) = (w*y.x, w*y.y)
#define CMAC(acc, ax, ay, b)                    \
  acc.x = fmaf(ax, b.x, acc.x);                 \
  acc.x = fmaf(ay, b.y, acc.x);                 \
  acc.y = fmaf(ax, b.y, acc.y);                 \
  acc.y = fmaf(-(ay), b.x, acc.y);

// (B,T,C,F) re/im planes -> (B,F,C,T) interleaved float2
__global__ __launch_bounds__(256) void k_tin(const float* __restrict__ in_re,
                                             const float* __restrict__ in_im,
                                             float2* __restrict__ Yt) {
  __shared__ float2 tile[32][33];
  int f0 = blockIdx.x * 32, t0 = blockIdx.y * 32;
  int b = blockIdx.z >> 3, c = blockIdx.z & 7;
  int tx = threadIdx.x & 31, ty = threadIdx.x >> 5;
#pragma unroll
  for (int ii = 0; ii < 4; ++ii) {
    int t = t0 + ty + 8 * ii, f = f0 + tx;
    if (t < Tt && f < Ff) {
      size_t idx = (((size_t)b * Tt + t) * Cc + c) * Ff + f;
      tile[ty + 8 * ii][tx] = make_float2(in_re[idx], in_im[idx]);
    }
  }
  __syncthreads();
#pragma unroll
  for (int ii = 0; ii < 4; ++ii) {
    int f = f0 + ty + 8 * ii, t = t0 + tx;
    if (f < Ff && t < Tt) {
      size_t o = (((size_t)b * Ff + f) * Cc + c) * Tt + t;
      Yt[o] = tile[tx][ty + 8 * ii];
    }
  }
}

// Unrolled accumulation body; u is a literal 0..4 so all %5 indices fold.
#define ABODY(u) do {                                                     \
  float2 ynd = Yd[tb + (u) + 4];                                          \
  float2 yne = Ye[tb + (u) + 4];                                          \
  float2 yep = Ye[tb + (u) + 7];                                          \
  float w = wl[tb + (u) + 7];                                             \
  wd[((u)+4)%5] = ynd; we[((u)+4)%5] = yne;                               \
  float ax[5], ay[5];                                                     \
  _Pragma("unroll")                                                       \
  for (int k = 0; k < 5; ++k) {                                           \
    float2 yr = wd[((u)+4-k)%5]; ax[k] = w*yr.x; ay[k] = w*yr.y;          \
  }                                                                       \
  _Pragma("unroll")                                                       \
  for (int l = 0; l < 5; ++l) {                                           \
    float2 yc = we[((u)+4-l)%5];                                          \
    _Pragma("unroll")                                                     \
    for (int k = 0; k < 5; ++k) { CMAC(rac[k][l], ax[k], ay[k], yc); }    \
  }                                                                       \
  _Pragma("unroll")                                                       \
  for (int k = 0; k < 5; ++k) { CMAC(pac[k], ax[k], ay[k], yep); }        \
} while (0)

// One block (512 thr) per (b,f): full 2-iteration WPE.
// Accumulation: 64-thread groups, thread=(d,e) owns 5x5 R-tile + 5 P via
// register sliding windows; 8-way t-split; atomic LDS merge; 1-barrier GJ solve.
__global__ void __launch_bounds__(512)
__attribute__((amdgpu_waves_per_eu(4, 4)))
k_wpe(const float2* __restrict__ Yt,
      float2* __restrict__ enh,
      const float* __restrict__ in_re,
      const float* __restrict__ in_im,
      const int* __restrict__ ilens,
      float* __restrict__ out_re,
      float* __restrict__ out_im,
      int load_direct, int store_direct) {
  __shared__ float2 Yl[Cc][TP];        // 8 x 602 complex = 38528 B
  __shared__ float2 RP[KC][RPW];       // [R | P] 40 x 53      = 16960 B
  __shared__ float wl[Tt];             // 2400 B   -> total 57888 B

  int bf = blockIdx.x;
  int b = bf / Ff, f = bf % Ff;
  int tid = threadIdx.x;               // 0..511
  int group = tid >> 6;                // t-split group (wave)
  int lane = tid & 63;
  int d = lane & 7;                    // row channel
  int e = lane >> 3;                   // col channel

  // apply-pass mapping: thread = (channel ae, t-strip astrip)
  int ae = tid & 7;
  int astrip = tid >> 3;               // 0..63

  // solve mapping: thread = (row, col-chunk), 480 active
  int srow = tid % KC;                 // const divisor -> magic mul, hoisted
  int scol = tid / KC;                 // 0..12

  // ---- stage Y into LDS
  if (!load_direct) {
    const float4* Yg = (const float4*)(Yt + (size_t)bf * (Cc * Tt));
    for (int i = tid; i < Cc * Tt / 2; i += 512) {
      float4 v = Yg[i];
      int c = i / (Tt / 2), t2 = (i % (Tt / 2)) * 2;
      *(float4*)&Yl[c][t2] = v;        // 16B aligned: 602*c + t2 even
    }
  } else {
    for (int i = tid; i < Cc * Tt; i += 512) {
      int c = i / Tt, t = i % Tt;
      size_t idx = (((size_t)b * Tt + t) * Cc + c) * Ff + f;
      Yl[c][t] = make_float2(in_re[idx], in_im[idx]);
    }
  }
  __syncthreads();

  const float2* Yd = &Yl[d][0];
  const float2* Ye = &Yl[e][0];

  int tA = (TQ * group) >> 3;
  int tB = (TQ * (group + 1)) >> 3;

  for (int iter = 0; iter < 3; ++iter) {
    // ---- weights (iter 0 from Y); iter 1: apply filter -> weights; iter 2: apply -> store
    if (iter == 0) {
      for (int t = tid; t < Tt; t += 512) {
        float s = 0.f;
#pragma unroll
        for (int c = 0; c < Cc; ++c) { float2 y = Yl[c][t]; s += y.x*y.x + y.y*y.y; }
        wl[t] = 1.0f / fmaxf(s * 0.125f, EPSF);
      }
    } else {
      // hoist this thread's filter column G[:, ae] into registers (40 float2)
      float2 g[TAPS][Cc];
#pragma unroll
      for (int p = 0; p < TAPS; ++p)
#pragma unroll
        for (int dd = 0; dd < Cc; ++dd)
          g[p][dd] = RP[p * Cc + dd][KC + ae];
      int il = (iter == 2 && store_direct) ? ilens[b] : Tt;
      for (int t = astrip; t < Tt; t += 64) {
        float2 acc = Yl[ae][t];
#pragma unroll
        for (int p = 0; p < TAPS; ++p) {
          int ts = t - DELAY - p;
          if (ts >= 0) {
#pragma unroll
            for (int dd = 0; dd < Cc; ++dd) {
              float2 u = Yl[dd][ts];          // broadcast across the 8 ae-lanes
              float2 G = g[p][dd];
              acc.x -= G.x*u.x - G.y*u.y;
              acc.y -= G.x*u.y + G.y*u.x;
            }
          }
        }
        if (iter == 1) {
          float s = acc.x*acc.x + acc.y*acc.y;
          s += __shfl_xor(s, 1);
          s += __shfl_xor(s, 2);
          s += __shfl_xor(s, 4);              // sum over 8 channels of this t
          if (ae == 0) wl[t] = 1.0f / fmaxf(s * 0.125f, EPSF);
        } else {
          if (!store_direct) {
            enh[(size_t)bf * (Cc * Tt) + ae * Tt + t] = acc;
          } else {
            float2 v = (t < il) ? acc : make_float2(0.f, 0.f);
            size_t idx = (((size_t)b * Tt + t) * Cc + ae) * Ff + f;
            out_re[idx] = v.x;
            out_im[idx] = v.y;
          }
        }
      }
    }
    if (iter == 2) break;
    __syncthreads();   // (A) wl ready; apply-phase G reads done

    // ---- zero [R | P], eps folded onto diagonal (visible after barrier B)
    for (int idx = tid; idx < KC * NC; idx += 512) {
      int r = idx / NC, c = idx - r * NC;
      RP[r][c] = make_float2((r == c) ? EPSF : 0.f, 0.f);
    }

    // ---- accumulate: per-thread 5x5+5 tile, register sliding windows
    float2 rac[5][5], pac[5];
#pragma unroll
    for (int k = 0; k < 5; ++k) {
#pragma unroll
      for (int l = 0; l < 5; ++l) rac[k][l] = make_float2(0.f, 0.f);
      pac[k] = make_float2(0.f, 0.f);
    }

    float2 wd[5], we[5];
#pragma unroll
    for (int i = 0; i < 4; ++i) { wd[i] = Yd[tA + i]; we[i] = Ye[tA + i]; }

    int tb = tA;
    for (; tb + 5 <= tB; tb += 5) {
      ABODY(0); ABODY(1); ABODY(2); ABODY(3); ABODY(4);
    }
    for (int t = tb; t < tB; ++t) {    // tail (<=4 iters): read fresh
      float2 yep = Ye[t + 7];
      float w = wl[t + 7];
      float ax[5], ay[5];
#pragma unroll
      for (int k = 0; k < 5; ++k) {
        float2 yr = Yd[t + 4 - k]; ax[k] = w*yr.x; ay[k] = w*yr.y;
      }
#pragma unroll
      for (int l = 0; l < 5; ++l) {
        float2 yc = Ye[t + 4 - l];
#pragma unroll
        for (int k = 0; k < 5; ++k) { CMAC(rac[k][l], ax[k], ay[k], yc); }
      }
#pragma unroll
      for (int k = 0; k < 5; ++k) { CMAC(pac[k], ax[k], ay[k], yep); }
    }

    __syncthreads();   // (B) zeros visible; all partials ready in registers

    // ---- merge all 8 group partials concurrently via LDS float atomics
#pragma unroll
    for (int k = 0; k < 5; ++k) {
#pragma unroll
      for (int l = 0; l < 5; ++l) {
        atomicAdd(&RP[k*8+d][l*8+e].x, rac[k][l].x);
        atomicAdd(&RP[k*8+d][l*8+e].y, rac[k][l].y);
      }
      atomicAdd(&RP[k*8+d][KC+e].x, pac[k].x);
      atomicAdd(&RP[k*8+d][KC+e].y, pac[k].y);
    }
    __syncthreads();   // (C) R,P complete

    // ---- unnormalized Gauss-Jordan on [R | P]: ONE barrier per step.
    // Step j: rows i!=j:  RP[i][k] -= (RP[i][j]/RP[j][j]) * RP[j][k], k>j.
    // Row j and column j are never written during step j -> no intra-step hazard.
    for (int j = 0; j < KC; ++j) {
      if (tid < 480 && srow != j) {
        float2 pv = RP[j][j];
        float idn = 1.0f / (pv.x*pv.x + pv.y*pv.y);
        float2 lij = RP[srow][j];
        float2 fij = make_float2((lij.x*pv.x + lij.y*pv.y) * idn,
                                 (lij.y*pv.x - lij.x*pv.y) * idn);
        for (int k = j + 1 + scol; k < NC; k += 12) {
          float2 c = RP[j][k];
          float sx = fij.x*c.x - fij.y*c.y;
          float sy = fij.x*c.y + fij.y*c.x;
          RP[srow][k].x -= sx;
          RP[srow][k].y -= sy;
        }
      }
      __syncthreads();
    }
    // R is now diagonal; X = R^-1 P obtained by scaling P-columns by 1/diag
    if (tid < KC * Cc) {               // 320 entries
      int i = tid >> 3, ee = tid & 7;
      float2 pv = RP[i][i];
      float idn = 1.0f / (pv.x*pv.x + pv.y*pv.y);
      float2 p2 = RP[i][KC + ee];
      RP[i][KC + ee] = make_float2((p2.x*pv.x + p2.y*pv.y) * idn,
                                   (p2.y*pv.x - p2.x*pv.y) * idn);
    }
    __syncthreads();
  }
}

// (B,F,C,T) float2 -> masked (B,T,C,F) re/im planes
__global__ __launch_bounds__(256) void k_tout(const float2* __restrict__ enh,
                                              const int* __restrict__ ilens,
                                              float* __restrict__ out_re,
                                              float* __restrict__ out_im) {
  __shared__ float2 tile[32][33];
  int t0 = blockIdx.x * 32, f0 = blockIdx.y * 32;
  int b = blockIdx.z >> 3, c = blockIdx.z & 7;
  int tx = threadIdx.x & 31, ty = threadIdx.x >> 5;
#pragma unroll
  for (int ii = 0; ii < 4; ++ii) {
    int f = f0 + ty + 8 * ii, t = t0 + tx;
    if (f < Ff && t < Tt)
      tile[ty + 8 * ii][tx] = enh[(((size_t)b * Ff + f) * Cc + c) * Tt + t];
  }
  __syncthreads();
  int il = ilens[b];
#pragma unroll
  for (int ii = 0; ii < 4; ++ii) {
    int t = t0 + ty + 8 * ii, f = f0 + tx;
    if (t < Tt && f < Ff) {
      float2 v = tile[tx][ty + 8 * ii];
      if (t >= il) v = make_float2(0.f, 0.f);
      size_t idx = (((size_t)b * Tt + t) * Cc + c) * Ff + f;
      out_re[idx] = v.x;
      out_im[idx] = v.y;
    }
  }
}

extern "C" void kernel_launch(void* const* d_in, const int* in_sizes, int n_in,
                              void* d_out, int out_size, void* d_ws, size_t ws_size,
                              hipStream_t stream) {
  const float* in_re = (const float*)d_in[0];
  const float* in_im = (const float*)d_in[1];
  const int* ilens = (const int*)d_in[2];
  float* out_re = (float*)d_out;
  float* out_im = out_re + NTOT;

  size_t ybytes = (size_t)Bb * Ff * Cc * Tt * sizeof(float2);  // 78,950,400 B
  int have_yt  = ws_size >= ybytes;
  int have_enh = ws_size >= 2 * ybytes;
  float2* Yt  = (float2*)d_ws;
  float2* enh = (float2*)((char*)d_ws + ybytes);

  if (have_yt) {
    dim3 g((Ff + 31) / 32, (Tt + 31) / 32, Bb * Cc);
    k_tin<<<g, dim3(256), 0, stream>>>(in_re, in_im, Yt);
  }
  {
    dim3 g(Bb * Ff);
    k_wpe<<<g, dim3(512), 0, stream>>>(Yt, enh, in_re, in_im, ilens,
                                       out_re, out_im,
                                       have_yt ? 0 : 1, have_enh ? 0 : 1);
  }
  if (have_enh) {
    dim3 g((Tt + 31) / 32, (Ff + 31) / 32, Bb * Cc);
    k_tout<<<g, dim3(256), 0, stream>>>(enh, ilens, out_re, out_im);
  }
}

// Round 2
// 1595.731 us; speedup vs baseline: 1.3654x; 1.3654x over previous
//
#include <hip/hip_runtime.h>
#include <hip/hip_bf16.h>

#define Bb 8
#define Tt 600
#define Cc 8
#define Ff 257
#define TAPS 5
#define DELAY 3
#define KC 40            // TAPS*C
#define NC 48            // KC + C (R columns | P columns)
#define RPW 53           // RP row stride (float2): 106 dwords, gcd(106%32=10,32)=2 -> 16-bank spread
#define TQ 593           // T - DELAY - TAPS + 1
#define TP 602           // Y LDS row stride (float2): conflict-free for channel-strided access
#define EPSF 1e-10f
#define NTOT (Bb*Tt*Cc*Ff)   // 9,868,800

// acc += conj(a)*b with a pre-scaled: (ax,ay) = (w*y.x, w*y.y)
#define CMAC(acc, ax, ay, b)                    \
  acc.x = fmaf(ax, b.x, acc.x);                 \
  acc.x = fmaf(ay, b.y, acc.x);                 \
  acc.y = fmaf(ax, b.y, acc.y);                 \
  acc.y = fmaf(-(ay), b.x, acc.y);

// (B,T,C,F) re/im planes -> (B,F,C,T) interleaved float2
__global__ __launch_bounds__(256) void k_tin(const float* __restrict__ in_re,
                                             const float* __restrict__ in_im,
                                             float2* __restrict__ Yt) {
  __shared__ float2 tile[32][33];
  int f0 = blockIdx.x * 32, t0 = blockIdx.y * 32;
  int b = blockIdx.z >> 3, c = blockIdx.z & 7;
  int tx = threadIdx.x & 31, ty = threadIdx.x >> 5;
#pragma unroll
  for (int ii = 0; ii < 4; ++ii) {
    int t = t0 + ty + 8 * ii, f = f0 + tx;
    if (t < Tt && f < Ff) {
      size_t idx = (((size_t)b * Tt + t) * Cc + c) * Ff + f;
      tile[ty + 8 * ii][tx] = make_float2(in_re[idx], in_im[idx]);
    }
  }
  __syncthreads();
#pragma unroll
  for (int ii = 0; ii < 4; ++ii) {
    int f = f0 + ty + 8 * ii, t = t0 + tx;
    if (f < Ff && t < Tt) {
      size_t o = (((size_t)b * Ff + f) * Cc + c) * Tt + t;
      Yt[o] = tile[tx][ty + 8 * ii];
    }
  }
}

// Unrolled accumulation body; u is a literal 0..4 so all %5 indices fold.
#define ABODY(u) do {                                                     \
  float2 ynd = Yd[tb + (u) + 4];                                          \
  float2 yne = Ye[tb + (u) + 4];                                          \
  float2 yep = Ye[tb + (u) + 7];                                          \
  float w = wl[tb + (u) + 7];                                             \
  wd[((u)+4)%5] = ynd; we[((u)+4)%5] = yne;                               \
  float ax[5], ay[5];                                                     \
  _Pragma("unroll")                                                       \
  for (int k = 0; k < 5; ++k) {                                           \
    float2 yr = wd[((u)+4-k)%5]; ax[k] = w*yr.x; ay[k] = w*yr.y;          \
  }                                                                       \
  _Pragma("unroll")                                                       \
  for (int l = 0; l < 5; ++l) {                                           \
    float2 yc = we[((u)+4-l)%5];                                          \
    _Pragma("unroll")                                                     \
    for (int k = 0; k < 5; ++k) { CMAC(rac[k][l], ax[k], ay[k], yc); }    \
  }                                                                       \
  _Pragma("unroll")                                                       \
  for (int k = 0; k < 5; ++k) { CMAC(pac[k], ax[k], ay[k], yep); }        \
} while (0)

// One block (512 thr) per (b,f): full 2-iteration WPE.
// Accumulation: 64-thread groups, thread=(d,e) owns 5x5 R-tile + 5 P via
// register sliding windows; 8-way t-split; atomic LDS merge; 1-barrier GJ solve.
// enh aliases Yt: each block stages its own Yt slice to LDS before writing it.
__global__ void __launch_bounds__(512, 4)
k_wpe(const float2* __restrict__ Yt,
      float2* __restrict__ enh,
      const float* __restrict__ in_re,
      const float* __restrict__ in_im,
      const int* __restrict__ ilens,
      float* __restrict__ out_re,
      float* __restrict__ out_im,
      int load_direct, int store_direct) {
  __shared__ float2 Yl[Cc][TP];        // 8 x 602 complex = 38528 B
  __shared__ float2 RP[KC][RPW];       // [R | P] 40 x 53      = 16960 B
  __shared__ float wl[Tt];             // 2400 B   -> total 57888 B

  int bf = blockIdx.x;
  int b = bf / Ff, f = bf % Ff;
  int tid = threadIdx.x;               // 0..511
  int group = tid >> 6;                // t-split group (wave)
  int lane = tid & 63;
  int d = lane & 7;                    // row channel
  int e = lane >> 3;                   // col channel

  // apply-pass mapping: thread = (channel ae, t-strip astrip)
  int ae = tid & 7;
  int astrip = tid >> 3;               // 0..63

  // solve mapping: thread = (row, col-chunk), 480 active
  int srow = tid % KC;                 // const divisor -> magic mul, hoisted
  int scol = tid / KC;                 // 0..12

  // ---- stage Y into LDS
  if (!load_direct) {
    const float4* Yg = (const float4*)(Yt + (size_t)bf * (Cc * Tt));
    for (int i = tid; i < Cc * Tt / 2; i += 512) {
      float4 v = Yg[i];
      int c = i / (Tt / 2), t2 = (i % (Tt / 2)) * 2;
      *(float4*)&Yl[c][t2] = v;        // 16B aligned: 602*c + t2 even
    }
  } else {
    for (int i = tid; i < Cc * Tt; i += 512) {
      int c = i / Tt, t = i % Tt;
      size_t idx = (((size_t)b * Tt + t) * Cc + c) * Ff + f;
      Yl[c][t] = make_float2(in_re[idx], in_im[idx]);
    }
  }
  __syncthreads();

  const float2* Yd = &Yl[d][0];
  const float2* Ye = &Yl[e][0];

  int tA = (TQ * group) >> 3;
  int tB = (TQ * (group + 1)) >> 3;

  for (int iter = 0; iter < 3; ++iter) {
    // ---- weights (iter 0 from Y); iter 1: apply filter -> weights; iter 2: apply -> store
    if (iter == 0) {
      for (int t = tid; t < Tt; t += 512) {
        float s = 0.f;
#pragma unroll
        for (int c = 0; c < Cc; ++c) { float2 y = Yl[c][t]; s += y.x*y.x + y.y*y.y; }
        wl[t] = 1.0f / fmaxf(s * 0.125f, EPSF);
      }
    } else {
      int il = (iter == 2 && store_direct) ? ilens[b] : Tt;
      for (int t = astrip; t < Tt; t += 64) {
        float2 acc = Yl[ae][t];
#pragma unroll
        for (int p = 0; p < TAPS; ++p) {
          int ts = t - DELAY - p;
          if (ts >= 0) {
#pragma unroll
            for (int dd = 0; dd < Cc; ++dd) {
              float2 u = Yl[dd][ts];             // same addr across 8 ae-lanes: broadcast
              float2 G = RP[p * Cc + dd][KC + ae]; // filter from the solve (LDS, 16-bank spread)
              acc.x -= G.x*u.x - G.y*u.y;
              acc.y -= G.x*u.y + G.y*u.x;
            }
          }
        }
        if (iter == 1) {
          float s = acc.x*acc.x + acc.y*acc.y;
          s += __shfl_xor(s, 1);
          s += __shfl_xor(s, 2);
          s += __shfl_xor(s, 4);              // sum over 8 channels of this t
          if (ae == 0) wl[t] = 1.0f / fmaxf(s * 0.125f, EPSF);
        } else {
          if (!store_direct) {
            enh[(size_t)bf * (Cc * Tt) + ae * Tt + t] = acc;  // overwrites own Yt slice
          } else {
            float2 v = (t < il) ? acc : make_float2(0.f, 0.f);
            size_t idx = (((size_t)b * Tt + t) * Cc + ae) * Ff + f;
            out_re[idx] = v.x;
            out_im[idx] = v.y;
          }
        }
      }
    }
    if (iter == 2) break;
    __syncthreads();   // (A) wl ready; apply-phase G reads done

    // ---- zero [R | P], eps folded onto diagonal (visible after barrier B)
    for (int idx = tid; idx < KC * NC; idx += 512) {
      int r = idx / NC, c = idx - r * NC;
      RP[r][c] = make_float2((r == c) ? EPSF : 0.f, 0.f);
    }

    // ---- accumulate: per-thread 5x5+5 tile, register sliding windows
    float2 rac[5][5], pac[5];
#pragma unroll
    for (int k = 0; k < 5; ++k) {
#pragma unroll
      for (int l = 0; l < 5; ++l) rac[k][l] = make_float2(0.f, 0.f);
      pac[k] = make_float2(0.f, 0.f);
    }

    float2 wd[5], we[5];
#pragma unroll
    for (int i = 0; i < 4; ++i) { wd[i] = Yd[tA + i]; we[i] = Ye[tA + i]; }

    int tb = tA;
    for (; tb + 5 <= tB; tb += 5) {
      ABODY(0); ABODY(1); ABODY(2); ABODY(3); ABODY(4);
    }
    for (int t = tb; t < tB; ++t) {    // tail (<=4 iters): read fresh
      float2 yep = Ye[t + 7];
      float w = wl[t + 7];
      float ax[5], ay[5];
#pragma unroll
      for (int k = 0; k < 5; ++k) {
        float2 yr = Yd[t + 4 - k]; ax[k] = w*yr.x; ay[k] = w*yr.y;
      }
#pragma unroll
      for (int l = 0; l < 5; ++l) {
        float2 yc = Ye[t + 4 - l];
#pragma unroll
        for (int k = 0; k < 5; ++k) { CMAC(rac[k][l], ax[k], ay[k], yc); }
      }
#pragma unroll
      for (int k = 0; k < 5; ++k) { CMAC(pac[k], ax[k], ay[k], yep); }
    }

    __syncthreads();   // (B) zeros visible; all partials ready in registers

    // ---- merge all 8 group partials concurrently via LDS float atomics
#pragma unroll
    for (int k = 0; k < 5; ++k) {
#pragma unroll
      for (int l = 0; l < 5; ++l) {
        atomicAdd(&RP[k*8+d][l*8+e].x, rac[k][l].x);
        atomicAdd(&RP[k*8+d][l*8+e].y, rac[k][l].y);
      }
      atomicAdd(&RP[k*8+d][KC+e].x, pac[k].x);
      atomicAdd(&RP[k*8+d][KC+e].y, pac[k].y);
    }
    __syncthreads();   // (C) R,P complete

    // ---- unnormalized Gauss-Jordan on [R | P]: ONE barrier per step.
    // Step j: rows i!=j:  RP[i][k] -= (RP[i][j]/RP[j][j]) * RP[j][k], k>j.
    // Row j and column j are never written during step j -> no intra-step hazard.
    for (int j = 0; j < KC; ++j) {
      if (tid < 480 && srow != j) {
        float2 pv = RP[j][j];
        float idn = 1.0f / (pv.x*pv.x + pv.y*pv.y);
        float2 lij = RP[srow][j];
        float2 fij = make_float2((lij.x*pv.x + lij.y*pv.y) * idn,
                                 (lij.y*pv.x - lij.x*pv.y) * idn);
        for (int k = j + 1 + scol; k < NC; k += 12) {
          float2 c = RP[j][k];
          float sx = fij.x*c.x - fij.y*c.y;
          float sy = fij.x*c.y + fij.y*c.x;
          RP[srow][k].x -= sx;
          RP[srow][k].y -= sy;
        }
      }
      __syncthreads();
    }
    // R is now diagonal; X = R^-1 P obtained by scaling P-columns by 1/diag
    if (tid < KC * Cc) {               // 320 entries
      int i = tid >> 3, ee = tid & 7;
      float2 pv = RP[i][i];
      float idn = 1.0f / (pv.x*pv.x + pv.y*pv.y);
      float2 p2 = RP[i][KC + ee];
      RP[i][KC + ee] = make_float2((p2.x*pv.x + p2.y*pv.y) * idn,
                                   (p2.y*pv.x - p2.x*pv.y) * idn);
    }
    __syncthreads();
  }
}

// (B,F,C,T) float2 -> masked (B,T,C,F) re/im planes
__global__ __launch_bounds__(256) void k_tout(const float2* __restrict__ enh,
                                              const int* __restrict__ ilens,
                                              float* __restrict__ out_re,
                                              float* __restrict__ out_im) {
  __shared__ float2 tile[32][33];
  int t0 = blockIdx.x * 32, f0 = blockIdx.y * 32;
  int b = blockIdx.z >> 3, c = blockIdx.z & 7;
  int tx = threadIdx.x & 31, ty = threadIdx.x >> 5;
#pragma unroll
  for (int ii = 0; ii < 4; ++ii) {
    int f = f0 + ty + 8 * ii, t = t0 + tx;
    if (f < Ff && t < Tt)
      tile[ty + 8 * ii][tx] = enh[(((size_t)b * Ff + f) * Cc + c) * Tt + t];
  }
  __syncthreads();
  int il = ilens[b];
#pragma unroll
  for (int ii = 0; ii < 4; ++ii) {
    int t = t0 + ty + 8 * ii, f = f0 + tx;
    if (t < Tt && f < Ff) {
      float2 v = tile[tx][ty + 8 * ii];
      if (t >= il) v = make_float2(0.f, 0.f);
      size_t idx = (((size_t)b * Tt + t) * Cc + c) * Ff + f;
      out_re[idx] = v.x;
      out_im[idx] = v.y;
    }
  }
}

extern "C" void kernel_launch(void* const* d_in, const int* in_sizes, int n_in,
                              void* d_out, int out_size, void* d_ws, size_t ws_size,
                              hipStream_t stream) {
  const float* in_re = (const float*)d_in[0];
  const float* in_im = (const float*)d_in[1];
  const int* ilens = (const int*)d_in[2];
  float* out_re = (float*)d_out;
  float* out_im = out_re + NTOT;

  size_t ybytes = (size_t)Bb * Ff * Cc * Tt * sizeof(float2);  // 78,950,400 B
  int have_yt = ws_size >= ybytes;
  // enh ALIASES Yt: k_wpe block bf stages Yt[bf] into LDS before writing enh[bf],
  // and no block touches another block's slice -> race-free, halves ws need.
  float2* Yt  = (float2*)d_ws;
  float2* enh = (float2*)d_ws;

  if (have_yt) {
    dim3 g((Ff + 31) / 32, (Tt + 31) / 32, Bb * Cc);
    k_tin<<<g, dim3(256), 0, stream>>>(in_re, in_im, Yt);
  }
  {
    dim3 g(Bb * Ff);
    k_wpe<<<g, dim3(512), 0, stream>>>(Yt, enh, in_re, in_im, ilens,
                                       out_re, out_im,
                                       have_yt ? 0 : 1, have_yt ? 0 : 1);
  }
  if (have_yt) {
    dim3 g((Tt + 31) / 32, (Ff + 31) / 32, Bb * Cc);
    k_tout<<<g, dim3(256), 0, stream>>>(enh, ilens, out_re, out_im);
  }
}

// Round 3
// 1129.022 us; speedup vs baseline: 1.9298x; 1.4134x over previous
//
#include <hip/hip_runtime.h>
#include <hip/hip_bf16.h>

#define Bb 8
#define Tt 600
#define Cc 8
#define Ff 257
#define TAPS 5
#define DELAY 3
#define KC 40            // TAPS*C
#define NC 48            // KC + C (R columns | P columns)
#define RPW 53           // RP row stride (float2): 106 dwords, gcd(106,32)=2 -> 16-bank row spread
#define TQ 593           // T - DELAY - TAPS + 1
#define TP 602           // Y LDS row stride (float2): conflict-free for channel-strided access
#define EPSF 1e-10f
#define NTOT (Bb*Tt*Cc*Ff)   // 9,868,800

__device__ __forceinline__ float2 cmul2(float2 a, float2 b) {
  return make_float2(a.x*b.x - a.y*b.y, a.x*b.y + a.y*b.x);
}

// acc += conj(a)*b with a pre-scaled: (ax,ay) = (w*y.x, w*y.y)
#define CMAC(acc, ax, ay, b)                    \
  acc.x = fmaf(ax, b.x, acc.x);                 \
  acc.x = fmaf(ay, b.y, acc.x);                 \
  acc.y = fmaf(ax, b.y, acc.y);                 \
  acc.y = fmaf(-(ay), b.x, acc.y);

// (B,T,C,F) re/im planes -> (B,F,C,T) interleaved float2
__global__ __launch_bounds__(256) void k_tin(const float* __restrict__ in_re,
                                             const float* __restrict__ in_im,
                                             float2* __restrict__ Yt) {
  __shared__ float2 tile[32][33];
  int f0 = blockIdx.x * 32, t0 = blockIdx.y * 32;
  int b = blockIdx.z >> 3, c = blockIdx.z & 7;
  int tx = threadIdx.x & 31, ty = threadIdx.x >> 5;
#pragma unroll
  for (int ii = 0; ii < 4; ++ii) {
    int t = t0 + ty + 8 * ii, f = f0 + tx;
    if (t < Tt && f < Ff) {
      size_t idx = (((size_t)b * Tt + t) * Cc + c) * Ff + f;
      tile[ty + 8 * ii][tx] = make_float2(in_re[idx], in_im[idx]);
    }
  }
  __syncthreads();
#pragma unroll
  for (int ii = 0; ii < 4; ++ii) {
    int f = f0 + ty + 8 * ii, t = t0 + tx;
    if (f < Ff && t < Tt) {
      size_t o = (((size_t)b * Ff + f) * Cc + c) * Tt + t;
      Yt[o] = tile[tx][ty + 8 * ii];
    }
  }
}

// Unrolled accumulation body; u is a literal 0..4 so all %5 indices fold.
#define ABODY(u) do {                                                     \
  float2 ynd = Yd[tb + (u) + 4];                                          \
  float2 yne = Ye[tb + (u) + 4];                                          \
  float2 yep = Ye[tb + (u) + 7];                                          \
  float w = wl[tb + (u) + 7];                                             \
  wd[((u)+4)%5] = ynd; we[((u)+4)%5] = yne;                               \
  float ax[5], ay[5];                                                     \
  _Pragma("unroll")                                                       \
  for (int k = 0; k < 5; ++k) {                                           \
    float2 yr = wd[((u)+4-k)%5]; ax[k] = w*yr.x; ay[k] = w*yr.y;          \
  }                                                                       \
  _Pragma("unroll")                                                       \
  for (int l = 0; l < 5; ++l) {                                           \
    float2 yc = we[((u)+4-l)%5];                                          \
    _Pragma("unroll")                                                     \
    for (int k = 0; k < 5; ++k) { CMAC(rac[k][l], ax[k], ay[k], yc); }    \
  }                                                                       \
  _Pragma("unroll")                                                       \
  for (int k = 0; k < 5; ++k) { CMAC(pac[k], ax[k], ay[k], yep); }        \
} while (0)

// One block (512 thr) per (b,f): full 2-iteration WPE.
// Accumulation: 64-thread groups, thread=(d,e) owns 5x5 R-tile + 5 P via
// register sliding windows; 8-way t-split; sequential wave merge (NO float
// LDS atomics -- hipcc lowers those to CAS loops); 1-barrier GJ solve.
// enh aliases Yt: each block stages its own Yt slice to LDS before writing it.
__global__ void __launch_bounds__(512, 4)
k_wpe(const float2* __restrict__ Yt,
      float2* __restrict__ enh,
      const float* __restrict__ in_re,
      const float* __restrict__ in_im,
      const int* __restrict__ ilens,
      float* __restrict__ out_re,
      float* __restrict__ out_im,
      int load_direct, int store_direct) {
  __shared__ float2 Yl[Cc][TP];        // 8 x 602 complex = 38528 B
  __shared__ float2 RP[KC][RPW];       // [R | P] 40 x 53      = 16960 B
  __shared__ float wl[Tt];             // 2400 B   -> total 57888 B

  int bf = blockIdx.x;
  int b = bf / Ff, f = bf % Ff;
  int tid = threadIdx.x;               // 0..511
  int group = tid >> 6;                // t-split group (wave)
  int lane = tid & 63;
  int d = lane & 7;                    // row channel
  int e = lane >> 3;                   // col channel

  // solve mapping: thread = (row, col-chunk), 480 active
  int srow = tid % KC;                 // const divisor -> magic mul, hoisted
  int scol = tid / KC;                 // 0..12

  // ---- stage Y into LDS
  if (!load_direct) {
    const float4* Yg = (const float4*)(Yt + (size_t)bf * (Cc * Tt));
    for (int i = tid; i < Cc * Tt / 2; i += 512) {
      float4 v = Yg[i];
      int c = i / (Tt / 2), t2 = (i % (Tt / 2)) * 2;
      *(float4*)&Yl[c][t2] = v;        // 16B aligned: 602*c + t2 even
    }
  } else {
    for (int i = tid; i < Cc * Tt; i += 512) {
      int c = i / Tt, t = i % Tt;
      size_t idx = (((size_t)b * Tt + t) * Cc + c) * Ff + f;
      Yl[c][t] = make_float2(in_re[idx], in_im[idx]);
    }
  }
  __syncthreads();

  const float2* Yd = &Yl[d][0];
  const float2* Ye = &Yl[e][0];

  int tA = (TQ * group) >> 3;
  int tB = (TQ * (group + 1)) >> 3;

  for (int iter = 0; iter < 3; ++iter) {
    // ---- weights (iter 0 from Y); iter 1: apply filter -> weights; iter 2: apply -> store
    if (iter == 0) {
      for (int t = tid; t < Tt; t += 512) {
        float s = 0.f;
#pragma unroll
        for (int c = 0; c < Cc; ++c) { float2 y = Yl[c][t]; s += y.x*y.x + y.y*y.y; }
        wl[t] = 1.0f / fmaxf(s * 0.125f, EPSF);
      }
    } else {
      int il = (iter == 2 && store_direct) ? ilens[b] : Tt;
      for (int t = tid; t < Tt; t += 512) {
        float2 acc[Cc];
#pragma unroll
        for (int ee = 0; ee < Cc; ++ee) acc[ee] = Yl[ee][t];
        for (int p = 0; p < TAPS; ++p) {
          int ts = t - DELAY - p;
          if (ts < 0) break;   // zero-padded region
#pragma unroll
          for (int dd = 0; dd < Cc; ++dd) {
            float2 u = Yl[dd][ts];               // wave-uniform per dd? no: broadcast-free stride-1
#pragma unroll
            for (int ee = 0; ee < Cc; ++ee) {
              float2 g = RP[p * Cc + dd][KC + ee];  // uniform addr across wave -> broadcast
              acc[ee].x -= g.x*u.x - g.y*u.y;
              acc[ee].y -= g.x*u.y + g.y*u.x;
            }
          }
        }
        if (iter == 1) {
          float s = 0.f;
#pragma unroll
          for (int ee = 0; ee < Cc; ++ee) s += acc[ee].x*acc[ee].x + acc[ee].y*acc[ee].y;
          wl[t] = 1.0f / fmaxf(s * 0.125f, EPSF);
        } else {
          if (!store_direct) {
            float2* Eg = enh + (size_t)bf * (Cc * Tt);
#pragma unroll
            for (int ee = 0; ee < Cc; ++ee) Eg[ee * Tt + t] = acc[ee];  // own Yt slice
          } else {
            bool live = (t < il);
#pragma unroll
            for (int ee = 0; ee < Cc; ++ee) {
              float2 v = live ? acc[ee] : make_float2(0.f, 0.f);
              size_t idx = (((size_t)b * Tt + t) * Cc + ee) * Ff + f;
              out_re[idx] = v.x;
              out_im[idx] = v.y;
            }
          }
        }
      }
    }
    if (iter == 2) break;
    __syncthreads();   // (A) wl ready; apply-phase G reads done

    // ---- accumulate: per-thread 5x5+5 tile, register sliding windows
    float2 rac[5][5], pac[5];
#pragma unroll
    for (int k = 0; k < 5; ++k) {
#pragma unroll
      for (int l = 0; l < 5; ++l) rac[k][l] = make_float2(0.f, 0.f);
      pac[k] = make_float2(0.f, 0.f);
    }

    float2 wd[5], we[5];
#pragma unroll
    for (int i = 0; i < 4; ++i) { wd[i] = Yd[tA + i]; we[i] = Ye[tA + i]; }

    int tb = tA;
    for (; tb + 5 <= tB; tb += 5) {
      ABODY(0); ABODY(1); ABODY(2); ABODY(3); ABODY(4);
    }
    for (int t = tb; t < tB; ++t) {    // tail (<=4 iters): read fresh
      float2 yep = Ye[t + 7];
      float w = wl[t + 7];
      float ax[5], ay[5];
#pragma unroll
      for (int k = 0; k < 5; ++k) {
        float2 yr = Yd[t + 4 - k]; ax[k] = w*yr.x; ay[k] = w*yr.y;
      }
#pragma unroll
      for (int l = 0; l < 5; ++l) {
        float2 yc = Ye[t + 4 - l];
#pragma unroll
        for (int k = 0; k < 5; ++k) { CMAC(rac[k][l], ax[k], ay[k], yc); }
      }
#pragma unroll
      for (int k = 0; k < 5; ++k) { CMAC(pac[k], ax[k], ay[k], yep); }
    }

    // ---- merge the 8 group partials into RP (wave-uniform branch per pass).
    // Pass 0 WRITES (no zero-init needed) and folds the EPS regularizer onto
    // the diagonal (k==l && d==e). Plain LDS read/add/write: no FP atomics.
    for (int gpass = 0; gpass < 8; ++gpass) {
      if (group == gpass) {
        if (gpass == 0) {
#pragma unroll
          for (int k = 0; k < 5; ++k) {
#pragma unroll
            for (int l = 0; l < 5; ++l) {
              float2 v = rac[k][l];
              if (k == l && d == e) v.x += EPSF;
              RP[k*8+d][l*8+e] = v;
            }
            RP[k*8+d][KC+e] = pac[k];
          }
        } else {
#pragma unroll
          for (int k = 0; k < 5; ++k) {
#pragma unroll
            for (int l = 0; l < 5; ++l) {
              float2 v = RP[k*8+d][l*8+e];
              v.x += rac[k][l].x; v.y += rac[k][l].y;
              RP[k*8+d][l*8+e] = v;
            }
            float2 v = RP[k*8+d][KC+e];
            v.x += pac[k].x; v.y += pac[k].y;
            RP[k*8+d][KC+e] = v;
          }
        }
      }
      __syncthreads();
    }

    // ---- unnormalized Gauss-Jordan on [R | P]: ONE barrier per step.
    // Step j: rows i!=j:  RP[i][k] -= (RP[i][j]/RP[j][j]) * RP[j][k], k>j.
    // Row j and column j are never written during step j -> no intra-step hazard.
    for (int j = 0; j < KC; ++j) {
      if (tid < 480 && srow != j) {
        float2 pv = RP[j][j];
        float idn = 1.0f / (pv.x*pv.x + pv.y*pv.y);
        float2 lij = RP[srow][j];
        float2 fij = make_float2((lij.x*pv.x + lij.y*pv.y) * idn,
                                 (lij.y*pv.x - lij.x*pv.y) * idn);
        for (int k = j + 1 + scol; k < NC; k += 12) {
          float2 c = RP[j][k];
          float sx = fij.x*c.x - fij.y*c.y;
          float sy = fij.x*c.y + fij.y*c.x;
          RP[srow][k].x -= sx;
          RP[srow][k].y -= sy;
        }
      }
      __syncthreads();
    }
    // R is now diagonal; X = R^-1 P obtained by scaling P-columns by 1/diag
    if (tid < KC * Cc) {               // 320 entries
      int i = tid >> 3, ee = tid & 7;
      float2 pv = RP[i][i];
      float idn = 1.0f / (pv.x*pv.x + pv.y*pv.y);
      float2 p2 = RP[i][KC + ee];
      RP[i][KC + ee] = make_float2((p2.x*pv.x + p2.y*pv.y) * idn,
                                   (p2.y*pv.x - p2.x*pv.y) * idn);
    }
    __syncthreads();
  }
}

// (B,F,C,T) float2 -> masked (B,T,C,F) re/im planes
__global__ __launch_bounds__(256) void k_tout(const float2* __restrict__ enh,
                                              const int* __restrict__ ilens,
                                              float* __restrict__ out_re,
                                              float* __restrict__ out_im) {
  __shared__ float2 tile[32][33];
  int t0 = blockIdx.x * 32, f0 = blockIdx.y * 32;
  int b = blockIdx.z >> 3, c = blockIdx.z & 7;
  int tx = threadIdx.x & 31, ty = threadIdx.x >> 5;
#pragma unroll
  for (int ii = 0; ii < 4; ++ii) {
    int f = f0 + ty + 8 * ii, t = t0 + tx;
    if (f < Ff && t < Tt)
      tile[ty + 8 * ii][tx] = enh[(((size_t)b * Ff + f) * Cc + c) * Tt + t];
  }
  __syncthreads();
  int il = ilens[b];
#pragma unroll
  for (int ii = 0; ii < 4; ++ii) {
    int t = t0 + ty + 8 * ii, f = f0 + tx;
    if (t < Tt && f < Ff) {
      float2 v = tile[tx][ty + 8 * ii];
      if (t >= il) v = make_float2(0.f, 0.f);
      size_t idx = (((size_t)b * Tt + t) * Cc + c) * Ff + f;
      out_re[idx] = v.x;
      out_im[idx] = v.y;
    }
  }
}

extern "C" void kernel_launch(void* const* d_in, const int* in_sizes, int n_in,
                              void* d_out, int out_size, void* d_ws, size_t ws_size,
                              hipStream_t stream) {
  const float* in_re = (const float*)d_in[0];
  const float* in_im = (const float*)d_in[1];
  const int* ilens = (const int*)d_in[2];
  float* out_re = (float*)d_out;
  float* out_im = out_re + NTOT;

  size_t ybytes = (size_t)Bb * Ff * Cc * Tt * sizeof(float2);  // 78,950,400 B
  int have_yt = ws_size >= ybytes;
  // enh ALIASES Yt: k_wpe block bf stages Yt[bf] into LDS before writing enh[bf],
  // and no block touches another block's slice -> race-free, halves ws need.
  float2* Yt  = (float2*)d_ws;
  float2* enh = (float2*)d_ws;

  if (have_yt) {
    dim3 g((Ff + 31) / 32, (Tt + 31) / 32, Bb * Cc);
    k_tin<<<g, dim3(256), 0, stream>>>(in_re, in_im, Yt);
  }
  {
    dim3 g(Bb * Ff);
    k_wpe<<<g, dim3(512), 0, stream>>>(Yt, enh, in_re, in_im, ilens,
                                       out_re, out_im,
                                       have_yt ? 0 : 1, have_yt ? 0 : 1);
  }
  if (have_yt) {
    dim3 g((Tt + 31) / 32, (Ff + 31) / 32, Bb * Cc);
    k_tout<<<g, dim3(256), 0, stream>>>(enh, ilens, out_re, out_im);
  }
}